// Round 1
// baseline (165.106 us; speedup 1.0000x reference)
//
#include <hip/hip_runtime.h>
#include <math.h>

#define BB 2
#define NN 512
#define NAB 128
#define NF 128
#define NG 32

// ---------------------------------------------------------------------------
// Kernel 1: rf = r @ W_af   (rows = B*N = 1024, K = NAB = 128, out NF = 128)
// ---------------------------------------------------------------------------
__global__ __launch_bounds__(128) void rf_kernel(const float* __restrict__ r,
                                                 const float* __restrict__ W_af,
                                                 float* __restrict__ rf) {
    const int row = blockIdx.x;      // 0..1023
    const int f   = threadIdx.x;     // 0..127
    __shared__ float sr[NAB];
    sr[f] = r[row * NAB + f];
    __syncthreads();
    float p0 = 0.f, p1 = 0.f, p2 = 0.f, p3 = 0.f;
    #pragma unroll 8
    for (int k = 0; k < NAB; k += 4) {
        p0 += sr[k + 0] * W_af[(k + 0) * NF + f];
        p1 += sr[k + 1] * W_af[(k + 1) * NF + f];
        p2 += sr[k + 2] * W_af[(k + 2) * NF + f];
        p3 += sr[k + 3] * W_af[(k + 3) * NF + f];
    }
    rf[row * NF + f] = (p0 + p1) + (p2 + p3);
}

// ---------------------------------------------------------------------------
// Kernel 2: fused gaussian-smearing + DistanceFilter2 + cfconv reduction.
// One block per (b,i). y[b,i,f] = sum_j A[b,i,j]*rf[b,j,f]*W(b,i,j,f)
// with W = es @ W_df2 + b_df2 computed on the fly (never materialized).
// Thread = (h = tid>>6 in 0..3, lane_f = tid&63); owns f in {lane_f, lane_f+64}
// and j = h mod 4. W_df2 columns held in VGPRs; es broadcast from LDS.
// ---------------------------------------------------------------------------
__global__ __launch_bounds__(256) void cfconv_kernel(
    const float* __restrict__ e, const float* __restrict__ A,
    const float* __restrict__ rf, const float* __restrict__ offsets,
    const float* __restrict__ widths, const float* __restrict__ W_df2,
    const float* __restrict__ b_df2, float* __restrict__ y) {

    const int bi  = blockIdx.x;        // b*N + i
    const int b   = bi / NN;
    const int tid = threadIdx.x;
    const int lane_f = tid & 63;
    const int h      = tid >> 6;       // 0..3 (wave-uniform)

    __shared__ float sA[NN];
    __shared__ float se[NN];
    __shared__ float ses[32][NG];      // es for a chunk of 32 j's
    __shared__ float soff[NG];
    __shared__ float scoef[NG];
    __shared__ float sred[4][NF];

    for (int t = tid; t < NN; t += 256) {
        sA[t] = A[bi * NN + t];
        se[t] = e[bi * NN + t];
    }
    if (tid < NG) {
        soff[tid] = offsets[tid];
        const float w = widths[tid];
        scoef[tid] = -0.5f / (w * w);
    }

    // W_df2 columns into registers (reused for all 512 j)
    float wc0[NG], wc1[NG];
    #pragma unroll
    for (int g = 0; g < NG; ++g) {
        wc0[g] = W_df2[g * NF + lane_f];
        wc1[g] = W_df2[g * NF + lane_f + 64];
    }
    const float bb0 = b_df2[lane_f];
    const float bb1 = b_df2[lane_f + 64];

    float acc0 = 0.f, acc1 = 0.f;
    __syncthreads();

    for (int c0 = 0; c0 < NN; c0 += 32) {
        // compute es for 32 j's: 1024 exps over 256 threads
        #pragma unroll
        for (int t = tid; t < 32 * NG; t += 256) {
            const int jj = t >> 5, g = t & 31;
            const float d = se[c0 + jj] - soff[g];
            ses[jj][g] = __expf(scoef[g] * d * d);
        }
        __syncthreads();

        for (int jj = h; jj < 32; jj += 4) {
            const int j  = c0 + jj;
            const float aj = sA[j];
            const float r0 = rf[(b * NN + j) * NF + lane_f];
            const float r1 = rf[(b * NN + j) * NF + lane_f + 64];
            const float4* es4 = (const float4*)ses[jj];
            float a0 = 0.f, a1 = 0.f, a2 = 0.f, a3 = 0.f;
            float c0p = 0.f, c1p = 0.f, c2p = 0.f, c3p = 0.f;
            #pragma unroll
            for (int q = 0; q < NG / 4; ++q) {
                const float4 ev = es4[q];
                a0  += ev.x * wc0[4 * q + 0];
                a1  += ev.y * wc0[4 * q + 1];
                a2  += ev.z * wc0[4 * q + 2];
                a3  += ev.w * wc0[4 * q + 3];
                c0p += ev.x * wc1[4 * q + 0];
                c1p += ev.y * wc1[4 * q + 1];
                c2p += ev.z * wc1[4 * q + 2];
                c3p += ev.w * wc1[4 * q + 3];
            }
            const float w0 = bb0 + ((a0 + a1) + (a2 + a3));
            const float w1 = bb1 + ((c0p + c1p) + (c2p + c3p));
            acc0 += aj * r0 * w0;
            acc1 += aj * r1 * w1;
        }
        __syncthreads();
    }

    // reduce over the 4 h-groups
    sred[h][lane_f]      = acc0;
    sred[h][lane_f + 64] = acc1;
    __syncthreads();
    if (tid < NF) {
        const float s = (sred[0][tid] + sred[1][tid]) + (sred[2][tid] + sred[3][tid]);
        y[bi * NF + tid] = s;
    }
}

// ---------------------------------------------------------------------------
// Kernel 3: out = ssp(y @ W_d1 + b_d1) @ W_d2 + b_d2, one block per row.
// ---------------------------------------------------------------------------
__device__ __forceinline__ float ssp(float x) {
    // softplus(x) - ln 2, numerically stable
    const float sp = (x > 0.f) ? (x + log1pf(__expf(-x))) : log1pf(__expf(x));
    return sp - 0.69314718055994530942f;
}

__global__ __launch_bounds__(128) void mlp_kernel(
    const float* __restrict__ y, const float* __restrict__ W_d1,
    const float* __restrict__ b_d1, const float* __restrict__ W_d2,
    const float* __restrict__ b_d2, float* __restrict__ out) {
    const int row = blockIdx.x;
    const int f   = threadIdx.x;
    __shared__ float sy[NF];
    __shared__ float sh[NAB];
    sy[f] = y[row * NF + f];
    __syncthreads();
    float p0 = 0.f, p1 = 0.f, p2 = 0.f, p3 = 0.f;
    #pragma unroll 8
    for (int k = 0; k < NF; k += 4) {
        p0 += sy[k + 0] * W_d1[(k + 0) * NAB + f];
        p1 += sy[k + 1] * W_d1[(k + 1) * NAB + f];
        p2 += sy[k + 2] * W_d1[(k + 2) * NAB + f];
        p3 += sy[k + 3] * W_d1[(k + 3) * NAB + f];
    }
    sh[f] = ssp(((p0 + p1) + (p2 + p3)) + b_d1[f]);
    __syncthreads();
    p0 = p1 = p2 = p3 = 0.f;
    #pragma unroll 8
    for (int k = 0; k < NAB; k += 4) {
        p0 += sh[k + 0] * W_d2[(k + 0) * NAB + f];
        p1 += sh[k + 1] * W_d2[(k + 1) * NAB + f];
        p2 += sh[k + 2] * W_d2[(k + 2) * NAB + f];
        p3 += sh[k + 3] * W_d2[(k + 3) * NAB + f];
    }
    out[row * NAB + f] = ((p0 + p1) + (p2 + p3)) + b_d2[f];
}

// ---------------------------------------------------------------------------
extern "C" void kernel_launch(void* const* d_in, const int* in_sizes, int n_in,
                              void* d_out, int out_size, void* d_ws, size_t ws_size,
                              hipStream_t stream) {
    const float* r       = (const float*)d_in[0];   // [B,N,NAB]
    const float* e       = (const float*)d_in[1];   // [B,N,N]
    const float* A       = (const float*)d_in[2];   // [B,N,N]
    const float* offsets = (const float*)d_in[3];   // [NG]
    const float* widths  = (const float*)d_in[4];   // [NG]
    // d_in[5] = W_df1, d_in[6] = b_df1 : reference discards this branch
    const float* W_df2   = (const float*)d_in[7];   // [NG,NF]
    const float* b_df2   = (const float*)d_in[8];   // [NF]
    const float* W_af    = (const float*)d_in[9];   // [NAB,NF]
    const float* W_d1    = (const float*)d_in[10];  // [NF,NAB]
    const float* b_d1    = (const float*)d_in[11];  // [NAB]
    const float* W_d2    = (const float*)d_in[12];  // [NAB,NAB]
    const float* b_d2    = (const float*)d_in[13];  // [NAB]
    float* out = (float*)d_out;                      // [B,N,NAB]

    float* rf = (float*)d_ws;                        // [B,N,NF]  512 KB
    float* yv = rf + BB * NN * NF;                   // [B,N,NF]  512 KB

    const int rows = BB * NN;                        // 1024
    rf_kernel<<<rows, 128, 0, stream>>>(r, W_af, rf);
    cfconv_kernel<<<rows, 256, 0, stream>>>(e, A, rf, offsets, widths,
                                            W_df2, b_df2, yv);
    mlp_kernel<<<rows, 128, 0, stream>>>(yv, W_d1, b_d1, W_d2, b_d2, out);
}

// Round 2
// 120.650 us; speedup vs baseline: 1.3685x; 1.3685x over previous
//
#include <hip/hip_runtime.h>
#include <math.h>

#define BB 2
#define NN 512
#define NAB 128
#define NF 128
#define NG 32

typedef _Float16 f16;
typedef f16 f16x8 __attribute__((ext_vector_type(8)));
typedef f16 f16x4 __attribute__((ext_vector_type(4)));
typedef float f32x4 __attribute__((ext_vector_type(4)));

#define TS 520          // T row stride in f16: 16B-aligned rows, bank-offset 4/row (2-way = free)
#define SS 132          // S row stride in f32

// ---------------------------------------------------------------------------
// prep_rf: rf = r @ W_af, output TRANSPOSED f16: rfT[b][f][j]  (B-operand layout)
// block = 256 threads handles 4 consecutive rows (all in one batch b).
// ---------------------------------------------------------------------------
__global__ __launch_bounds__(256) void prep_rf(const float* __restrict__ r,
                                               const float* __restrict__ W_af,
                                               f16* __restrict__ rfT) {
    const int tid = threadIdx.x;
    const int r0  = blockIdx.x * 4;          // global row (b*512 + j)
    const int b   = r0 >> 9;
    const int j0  = r0 & 511;

    __shared__ float sr[4][128];
    __shared__ f16   st[128][8];             // [f][4 rows], padded to 8

    for (int t = tid; t < 512; t += 256)
        sr[t >> 7][t & 127] = r[(r0 + (t >> 7)) * NAB + (t & 127)];
    __syncthreads();

    const int f  = tid & 127;
    const int rh = tid >> 7;                 // 0..1 -> rows 2rh, 2rh+1
    float a0 = 0.f, a1 = 0.f;
    #pragma unroll 8
    for (int k = 0; k < NAB; ++k) {
        const float wv = W_af[k * NF + f];
        a0 += sr[2 * rh + 0][k] * wv;
        a1 += sr[2 * rh + 1][k] * wv;
    }
    st[f][2 * rh + 0] = (f16)a0;
    st[f][2 * rh + 1] = (f16)a1;
    __syncthreads();

    if (tid < 128) {
        f16x4 v;
        v[0] = st[tid][0]; v[1] = st[tid][1]; v[2] = st[tid][2]; v[3] = st[tid][3];
        *(f16x4*)(rfT + b * (NF * NN) + tid * NN + j0) = v;
    }
}

// ---------------------------------------------------------------------------
// Fused: gaussian smearing -> T=[A*es; A] -> MFMA S = T @ rf -> y -> MLP -> out
// One block per (b,i), 256 threads = 4 waves.
//   T (LDS, f16): rows 0..31 = A[i,j]*es[i,j,g]; row 32 = A[i,j]; rows 33..47
//   never written and never read downstream (their S rows are dead).
//   Wave w computes S columns [32w, 32w+32): 3 m-tiles x 2 n-tiles, K=512.
// ---------------------------------------------------------------------------
__global__ __launch_bounds__(256) void fused_kernel(
    const float* __restrict__ e, const float* __restrict__ A,
    const f16*  __restrict__ rfT,
    const float* __restrict__ offsets, const float* __restrict__ widths,
    const float* __restrict__ W_df2, const float* __restrict__ b_df2,
    const float* __restrict__ W_d1,  const float* __restrict__ b_d1,
    const float* __restrict__ W_d2,  const float* __restrict__ b_d2,
    float* __restrict__ out) {

    const int bi  = blockIdx.x;              // b*N + i
    const int b   = bi >> 9;
    const int tid = threadIdx.x;
    const int w    = tid >> 6;               // wave 0..3
    const int lane = tid & 63;
    const int q    = lane >> 4;              // quad 0..3
    const int n    = lane & 15;              // m for A-frag, n for B-frag

    __shared__ __align__(16) f16 Tsh[48 * TS];   // 49,920 B; reused as S (f32) later
    __shared__ float sconst[64];                 // [0:32)=offsets, [32:64)=coef
    __shared__ float sy[128];
    __shared__ float spart[2][128];

    if (tid < NG) {
        sconst[tid] = offsets[tid];
        const float wd = widths[tid];
        sconst[32 + tid] = -0.5f / (wd * wd);
    }
    __syncthreads();

    // ---- build T ----
    for (int jj = tid; jj < NN; jj += 256) {
        const float ev = e[bi * NN + jj];
        const float av = A[bi * NN + jj];
        #pragma unroll
        for (int g = 0; g < NG; ++g) {
            const float d = ev - sconst[g];
            Tsh[g * TS + jj] = (f16)(av * __expf(sconst[32 + g] * d * d));
        }
        Tsh[32 * TS + jj] = (f16)av;
    }
    __syncthreads();

    // ---- MFMA K-loop ----
    f32x4 acc[3][2];
    #pragma unroll
    for (int mt = 0; mt < 3; ++mt)
        #pragma unroll
        for (int nt = 0; nt < 2; ++nt)
            acc[mt][nt] = (f32x4){0.f, 0.f, 0.f, 0.f};

    const f16* Ab = Tsh + n * TS + q * 8;
    const f16* Bb = rfT + (size_t)b * (NF * NN) + (w * 32 + n) * NN + q * 8;

    #pragma unroll 4
    for (int k = 0; k < NN; k += 32) {
        const f16x8 a0 = *(const f16x8*)(Ab + k);
        const f16x8 a1 = *(const f16x8*)(Ab + 16 * TS + k);
        const f16x8 a2 = *(const f16x8*)(Ab + 32 * TS + k);
        const f16x8 b0 = *(const f16x8*)(Bb + k);
        const f16x8 b1 = *(const f16x8*)(Bb + 16 * NN + k);
        acc[0][0] = __builtin_amdgcn_mfma_f32_16x16x32_f16(a0, b0, acc[0][0], 0, 0, 0);
        acc[1][0] = __builtin_amdgcn_mfma_f32_16x16x32_f16(a1, b0, acc[1][0], 0, 0, 0);
        acc[2][0] = __builtin_amdgcn_mfma_f32_16x16x32_f16(a2, b0, acc[2][0], 0, 0, 0);
        acc[0][1] = __builtin_amdgcn_mfma_f32_16x16x32_f16(a0, b1, acc[0][1], 0, 0, 0);
        acc[1][1] = __builtin_amdgcn_mfma_f32_16x16x32_f16(a1, b1, acc[1][1], 0, 0, 0);
        acc[2][1] = __builtin_amdgcn_mfma_f32_16x16x32_f16(a2, b1, acc[2][1], 0, 0, 0);
    }

    __syncthreads();   // all waves done reading Tsh; reuse it as S (f32)
    float* S = (float*)Tsh;
    #pragma unroll
    for (int mt = 0; mt < 3; ++mt)
        #pragma unroll
        for (int nt = 0; nt < 2; ++nt)
            #pragma unroll
            for (int rr = 0; rr < 4; ++rr)
                S[(mt * 16 + q * 4 + rr) * SS + (w * 32 + nt * 16 + n)] = acc[mt][nt][rr];
    __syncthreads();

    // ---- y[f] = sum_g W_df2[g,f]*S[g,f] + b_df2[f]*S[32,f] ----
    if (tid < NF) {
        const int f = tid;
        float a = b_df2[f] * S[32 * SS + f];
        #pragma unroll 8
        for (int g = 0; g < NG; ++g)
            a += W_df2[g * NF + f] * S[g * SS + f];
        sy[f] = a;
    }
    __syncthreads();

    // ---- MLP layer 1: h = ssp(y @ W_d1 + b_d1) ----
    {
        const int f = tid & 127, hh = tid >> 7;   // hh wave-uniform
        float a = 0.f;
        #pragma unroll 8
        for (int k = hh * 64; k < hh * 64 + 64; ++k)
            a += sy[k] * W_d1[k * NAB + f];
        spart[hh][f] = a;
    }
    __syncthreads();
    float hreg = 0.f;
    if (tid < NAB) {
        const float x = spart[0][tid] + spart[1][tid] + b_d1[tid];
        const float sp = (x > 0.f) ? (x + log1pf(__expf(-x))) : log1pf(__expf(x));
        hreg = sp - 0.69314718055994530942f;
    }
    __syncthreads();
    if (tid < NAB) sy[tid] = hreg;                 // reuse sy for h
    __syncthreads();

    // ---- MLP layer 2: out = h @ W_d2 + b_d2 ----
    {
        const int f = tid & 127, hh = tid >> 7;
        float a = 0.f;
        #pragma unroll 8
        for (int k = hh * 64; k < hh * 64 + 64; ++k)
            a += sy[k] * W_d2[k * NAB + f];
        spart[hh][f] = a;
    }
    __syncthreads();
    if (tid < NAB)
        out[bi * NAB + tid] = spart[0][tid] + spart[1][tid] + b_d2[tid];
}

// ---------------------------------------------------------------------------
extern "C" void kernel_launch(void* const* d_in, const int* in_sizes, int n_in,
                              void* d_out, int out_size, void* d_ws, size_t ws_size,
                              hipStream_t stream) {
    const float* r       = (const float*)d_in[0];
    const float* e       = (const float*)d_in[1];
    const float* A       = (const float*)d_in[2];
    const float* offsets = (const float*)d_in[3];
    const float* widths  = (const float*)d_in[4];
    // d_in[5]/d_in[6]: W_df1/b_df1 — reference discards this branch
    const float* W_df2   = (const float*)d_in[7];
    const float* b_df2   = (const float*)d_in[8];
    const float* W_af    = (const float*)d_in[9];
    const float* W_d1    = (const float*)d_in[10];
    const float* b_d1    = (const float*)d_in[11];
    const float* W_d2    = (const float*)d_in[12];
    const float* b_d2    = (const float*)d_in[13];
    float* out = (float*)d_out;

    f16* rfT = (f16*)d_ws;                       // [B][128 f][512 j] f16 = 256 KB

    prep_rf<<<BB * NN / 4, 256, 0, stream>>>(r, W_af, rfT);
    fused_kernel<<<BB * NN, 256, 0, stream>>>(e, A, rfT, offsets, widths,
                                              W_df2, b_df2, W_d1, b_d1,
                                              W_d2, b_d2, out);
}

// Round 3
// 116.023 us; speedup vs baseline: 1.4230x; 1.0399x over previous
//
#include <hip/hip_runtime.h>
#include <math.h>

#define BB 2
#define NN 512
#define NAB 128
#define NF 128
#define NG 32

typedef _Float16 f16;
typedef f16 f16x8 __attribute__((ext_vector_type(8)));
typedef f16 f16x4 __attribute__((ext_vector_type(4)));
typedef float f32x4 __attribute__((ext_vector_type(4)));

#define TS 520          // T row stride (f16): rows 16B-aligned, +4-bank skew per row
#define SS 132          // S row stride (f32): +4-bank skew per row

// ---------------------------------------------------------------------------
// prep_rf: rf = r @ W_af, output TRANSPOSED f16: rfT[b][f][j]  (B-operand layout)
// ---------------------------------------------------------------------------
__global__ __launch_bounds__(256) void prep_rf(const float* __restrict__ r,
                                               const float* __restrict__ W_af,
                                               f16* __restrict__ rfT) {
    const int tid = threadIdx.x;
    const int r0  = blockIdx.x * 4;          // global row (b*512 + j)
    const int b   = r0 >> 9;
    const int j0  = r0 & 511;

    __shared__ float sr[4][128];
    __shared__ f16   st[128][8];

    for (int t = tid; t < 512; t += 256)
        sr[t >> 7][t & 127] = r[(r0 + (t >> 7)) * NAB + (t & 127)];
    __syncthreads();

    const int f  = tid & 127;
    const int rh = tid >> 7;
    float a0 = 0.f, a1 = 0.f;
    #pragma unroll 8
    for (int k = 0; k < NAB; ++k) {
        const float wv = W_af[k * NF + f];
        a0 += sr[2 * rh + 0][k] * wv;
        a1 += sr[2 * rh + 1][k] * wv;
    }
    st[f][2 * rh + 0] = (f16)a0;
    st[f][2 * rh + 1] = (f16)a1;
    __syncthreads();

    if (tid < 128) {
        f16x4 v;
        v[0] = st[tid][0]; v[1] = st[tid][1]; v[2] = st[tid][2]; v[3] = st[tid][3];
        *(f16x4*)(rfT + b * (NF * NN) + tid * NN + j0) = v;
    }
}

// ---------------------------------------------------------------------------
// Fused: gaussians -> T=[A*es; A] (LDS) -> MFMA S = T @ rfT^T (K-split across
// wave pairs) -> y -> MLP -> out.  One block per (b,i), 256 threads = 4 waves.
// Wave w: kh = w>>1 (k-half of 256), nh = w&1 (f-half of 64).
// ---------------------------------------------------------------------------
__global__ __launch_bounds__(256) void fused_kernel(
    const float* __restrict__ e, const float* __restrict__ A,
    const f16*  __restrict__ rfT,
    const float* __restrict__ offsets, const float* __restrict__ widths,
    const float* __restrict__ W_df2, const float* __restrict__ b_df2,
    const float* __restrict__ W_d1,  const float* __restrict__ b_d1,
    const float* __restrict__ W_d2,  const float* __restrict__ b_d2,
    float* __restrict__ out) {

    const int bi  = blockIdx.x;
    const int b   = bi >> 9;
    const int tid = threadIdx.x;
    const int w    = tid >> 6;
    const int lane = tid & 63;
    const int q    = lane >> 4;
    const int n    = lane & 15;

    __shared__ __align__(16) f16 Tsh[48 * TS];   // 49,920 B; reused as S (f32)
    __shared__ float sconst[64];
    __shared__ float sy[128];
    __shared__ float spart[2][128];

    if (tid < NG) {
        sconst[tid] = offsets[tid];
        const float wd = widths[tid];
        sconst[32 + tid] = -0.5f / (wd * wd);
    }

    // ---- build T: thread owns j-quad j0..j0+3, loops over g ----
    const int j0 = (tid & 127) * 4;
    const float4 ev = *(const float4*)(e + bi * NN + j0);
    const float4 av = *(const float4*)(A + bi * NN + j0);
    __syncthreads();                              // sconst ready

    #pragma unroll
    for (int i = 0; i < 16; ++i) {
        const int g = (tid >> 7) + 2 * i;         // wave-uniform
        const float off = sconst[g];
        const float cf  = sconst[32 + g];
        const float d0 = ev.x - off, d1 = ev.y - off;
        const float d2 = ev.z - off, d3 = ev.w - off;
        f16x4 v;
        v[0] = (f16)(av.x * __expf(cf * d0 * d0));
        v[1] = (f16)(av.y * __expf(cf * d1 * d1));
        v[2] = (f16)(av.z * __expf(cf * d2 * d2));
        v[3] = (f16)(av.w * __expf(cf * d3 * d3));
        *(f16x4*)(Tsh + g * TS + j0) = v;
    }
    if (tid < 128) {                              // row 32 = A itself
        f16x4 v;
        v[0] = (f16)av.x; v[1] = (f16)av.y; v[2] = (f16)av.z; v[3] = (f16)av.w;
        *(f16x4*)(Tsh + 32 * TS + j0) = v;
    }
    __syncthreads();

    // ---- MFMA K-loop (K-split) ----
    const int kh = w >> 1;                        // k-half: 0 or 1
    const int nh = w & 1;                         // f-half: 0 or 1

    f32x4 acc[3][4];
    #pragma unroll
    for (int mt = 0; mt < 3; ++mt)
        #pragma unroll
        for (int nt = 0; nt < 4; ++nt)
            acc[mt][nt] = (f32x4){0.f, 0.f, 0.f, 0.f};

    const f16* Abase = Tsh + n * TS + kh * 256 + q * 8;
    const f16* Bbase = rfT + (size_t)b * (NF * NN) + (nh * 64 + n) * NN + kh * 256 + q * 8;

    f16x8 bcur[4], bnext[4];
    #pragma unroll
    for (int nt = 0; nt < 4; ++nt)
        bcur[nt] = *(const f16x8*)(Bbase + nt * 16 * NN);

    #pragma unroll
    for (int kk = 0; kk < 8; ++kk) {
        const f16* Ak = Abase + kk * 32;
        const f16x8 a0 = *(const f16x8*)(Ak);
        const f16x8 a1 = *(const f16x8*)(Ak + 16 * TS);
        const f16x8 a2 = *(const f16x8*)(Ak + 32 * TS);
        if (kk < 7) {
            #pragma unroll
            for (int nt = 0; nt < 4; ++nt)
                bnext[nt] = *(const f16x8*)(Bbase + (kk + 1) * 32 + nt * 16 * NN);
        }
        #pragma unroll
        for (int nt = 0; nt < 4; ++nt) {
            acc[0][nt] = __builtin_amdgcn_mfma_f32_16x16x32_f16(a0, bcur[nt], acc[0][nt], 0, 0, 0);
            acc[1][nt] = __builtin_amdgcn_mfma_f32_16x16x32_f16(a1, bcur[nt], acc[1][nt], 0, 0, 0);
            acc[2][nt] = __builtin_amdgcn_mfma_f32_16x16x32_f16(a2, bcur[nt], acc[2][nt], 0, 0, 0);
        }
        #pragma unroll
        for (int nt = 0; nt < 4; ++nt) bcur[nt] = bnext[nt];
    }

    __syncthreads();                              // Tsh reads done; reuse as S
    float* S = (float*)Tsh;

    // kh=0 waves write their partial S; kh=1 waves then add theirs.
    // Only rows 0..31 (gaussians) and row 32 (A-row, mt=2/q=0/reg=0) are live.
    if (kh == 0) {
        #pragma unroll
        for (int mt = 0; mt < 2; ++mt)
            #pragma unroll
            for (int nt = 0; nt < 4; ++nt)
                #pragma unroll
                for (int rr = 0; rr < 4; ++rr)
                    S[(mt * 16 + q * 4 + rr) * SS + nh * 64 + nt * 16 + n] = acc[mt][nt][rr];
        if (q == 0) {
            #pragma unroll
            for (int nt = 0; nt < 4; ++nt)
                S[32 * SS + nh * 64 + nt * 16 + n] = acc[2][nt][0];
        }
    }
    __syncthreads();
    if (kh == 1) {
        #pragma unroll
        for (int mt = 0; mt < 2; ++mt)
            #pragma unroll
            for (int nt = 0; nt < 4; ++nt)
                #pragma unroll
                for (int rr = 0; rr < 4; ++rr)
                    S[(mt * 16 + q * 4 + rr) * SS + nh * 64 + nt * 16 + n] += acc[mt][nt][rr];
        if (q == 0) {
            #pragma unroll
            for (int nt = 0; nt < 4; ++nt)
                S[32 * SS + nh * 64 + nt * 16 + n] += acc[2][nt][0];
        }
    }
    __syncthreads();

    // ---- y[f] = sum_g W_df2[g,f]*S[g,f] + b_df2[f]*S[32,f]  (g split by half) ----
    {
        const int f = tid & 127;
        float a;
        if (tid < 128) {
            a = b_df2[f] * S[32 * SS + f];
            #pragma unroll
            for (int g = 0; g < 16; ++g)
                a += W_df2[g * NF + f] * S[g * SS + f];
        } else {
            a = 0.f;
            #pragma unroll
            for (int g = 16; g < 32; ++g)
                a += W_df2[g * NF + f] * S[g * SS + f];
        }
        spart[tid >> 7][f] = a;
    }
    __syncthreads();
    if (tid < 128) sy[tid] = spart[0][tid] + spart[1][tid];
    __syncthreads();

    // ---- MLP layer 1: h = ssp(y @ W_d1 + b_d1) ----
    {
        const int f = tid & 127, hh = tid >> 7;
        float a = 0.f;
        #pragma unroll 8
        for (int k = hh * 64; k < hh * 64 + 64; ++k)
            a += sy[k] * W_d1[k * NAB + f];
        spart[hh][f] = a;
    }
    __syncthreads();
    float hreg = 0.f;
    if (tid < NAB) {
        const float x = spart[0][tid] + spart[1][tid] + b_d1[tid];
        const float sp = (x > 0.f) ? (x + log1pf(__expf(-x))) : log1pf(__expf(x));
        hreg = sp - 0.69314718055994530942f;
    }
    __syncthreads();
    if (tid < NAB) sy[tid] = hreg;
    __syncthreads();

    // ---- MLP layer 2: out = h @ W_d2 + b_d2 ----
    {
        const int f = tid & 127, hh = tid >> 7;
        float a = 0.f;
        #pragma unroll 8
        for (int k = hh * 64; k < hh * 64 + 64; ++k)
            a += sy[k] * W_d2[k * NAB + f];
        spart[hh][f] = a;
    }
    __syncthreads();
    if (tid < NAB)
        out[bi * NAB + tid] = spart[0][tid] + spart[1][tid] + b_d2[tid];
}

// ---------------------------------------------------------------------------
extern "C" void kernel_launch(void* const* d_in, const int* in_sizes, int n_in,
                              void* d_out, int out_size, void* d_ws, size_t ws_size,
                              hipStream_t stream) {
    const float* r       = (const float*)d_in[0];
    const float* e       = (const float*)d_in[1];
    const float* A       = (const float*)d_in[2];
    const float* offsets = (const float*)d_in[3];
    const float* widths  = (const float*)d_in[4];
    // d_in[5]/d_in[6]: W_df1/b_df1 — reference discards this branch
    const float* W_df2   = (const float*)d_in[7];
    const float* b_df2   = (const float*)d_in[8];
    const float* W_af    = (const float*)d_in[9];
    const float* W_d1    = (const float*)d_in[10];
    const float* b_d1    = (const float*)d_in[11];
    const float* W_d2    = (const float*)d_in[12];
    const float* b_d2    = (const float*)d_in[13];
    float* out = (float*)d_out;

    f16* rfT = (f16*)d_ws;                       // [B][128 f][512 j] f16 = 256 KB

    prep_rf<<<BB * NN / 4, 256, 0, stream>>>(r, W_af, rfT);
    fused_kernel<<<BB * NN, 256, 0, stream>>>(e, A, rfT, offsets, widths,
                                              W_df2, b_df2, W_d1, b_d1,
                                              W_d2, b_d2, out);
}

// Round 4
// 110.463 us; speedup vs baseline: 1.4947x; 1.0503x over previous
//
#include <hip/hip_runtime.h>
#include <math.h>

#define BB 2
#define NN 512
#define NAB 128
#define NF 128
#define NG 32

typedef _Float16 f16;
typedef f16 f16x8 __attribute__((ext_vector_type(8)));
typedef f16 f16x4 __attribute__((ext_vector_type(4)));
typedef float f32x4 __attribute__((ext_vector_type(4)));

#define TS 520          // T row stride (f16): rows 16B-aligned, +4-bank skew per row
#define SS 132          // S row stride (f32)

// ---------------------------------------------------------------------------
// prep_rf: rf = r @ W_af, output TRANSPOSED f16: rfT[b][f][j]  (B-operand layout)
// ---------------------------------------------------------------------------
__global__ __launch_bounds__(256) void prep_rf(const float* __restrict__ r,
                                               const float* __restrict__ W_af,
                                               f16* __restrict__ rfT) {
    const int tid = threadIdx.x;
    const int r0  = blockIdx.x * 4;          // global row (b*512 + j)
    const int b   = r0 >> 9;
    const int j0  = r0 & 511;

    __shared__ float sr[4][128];
    __shared__ f16   st[128][8];

    for (int t = tid; t < 512; t += 256)
        sr[t >> 7][t & 127] = r[(r0 + (t >> 7)) * NAB + (t & 127)];
    __syncthreads();

    const int f  = tid & 127;
    const int rh = tid >> 7;
    float a0 = 0.f, a1 = 0.f;
    #pragma unroll 8
    for (int k = 0; k < NAB; ++k) {
        const float wv = W_af[k * NF + f];
        a0 += sr[2 * rh + 0][k] * wv;
        a1 += sr[2 * rh + 1][k] * wv;
    }
    st[f][2 * rh + 0] = (f16)a0;
    st[f][2 * rh + 1] = (f16)a1;
    __syncthreads();

    if (tid < 128) {
        f16x4 v;
        v[0] = st[tid][0]; v[1] = st[tid][1]; v[2] = st[tid][2]; v[3] = st[tid][3];
        *(f16x4*)(rfT + b * (NF * NN) + tid * NN + j0) = v;
    }
}

// ---------------------------------------------------------------------------
// Fused: gaussians -> T=[A*es; A] (33 rows, LDS) -> MFMA S = T @ rfT^T
// (K-split across wave pairs, partial-S buffers) -> y -> MLP -> out.
// One block per (b,i), 256 threads = 4 waves; wave w: kh=w>>1, nh=w&1.
// The third m-tile reads T row 32 with an n-independent (broadcast) address:
// effective A-tile rows are all copies of row 32, and only D row 0 is stored.
// ---------------------------------------------------------------------------
__global__ __launch_bounds__(256, 4) void fused_kernel(
    const float* __restrict__ e, const float* __restrict__ A,
    const f16*  __restrict__ rfT,
    const float* __restrict__ offsets, const float* __restrict__ widths,
    const float* __restrict__ W_df2, const float* __restrict__ b_df2,
    const float* __restrict__ W_d1,  const float* __restrict__ b_d1,
    const float* __restrict__ W_d2,  const float* __restrict__ b_d2,
    float* __restrict__ out) {

    const int bi  = blockIdx.x;
    const int b   = bi >> 9;
    const int tid = threadIdx.x;
    const int w    = tid >> 6;
    const int lane = tid & 63;
    const int q    = lane >> 4;
    const int n    = lane & 15;

    // union region: T (33*520 f16 = 34,320 B)  /  S pair (2*33*132 f32 = 34,848 B)
    __shared__ __align__(16) float smem[2 * 33 * SS];
    __shared__ float sconst[64];
    __shared__ float sy[128];
    __shared__ float spart[2][128];

    f16* Tsh = (f16*)smem;

    if (tid < NG) {
        sconst[tid] = offsets[tid];
        const float wd = widths[tid];
        sconst[32 + tid] = -0.5f / (wd * wd);
    }

    // ---- build T: thread owns j-quad, loops over g ----
    const int j0 = (tid & 127) * 4;
    const float4 ev = *(const float4*)(e + bi * NN + j0);
    const float4 av = *(const float4*)(A + bi * NN + j0);
    __syncthreads();                              // sconst ready

    #pragma unroll
    for (int i = 0; i < 16; ++i) {
        const int g = (tid >> 7) + 2 * i;         // wave-uniform
        const float off = sconst[g];
        const float cf  = sconst[32 + g];
        const float d0 = ev.x - off, d1 = ev.y - off;
        const float d2 = ev.z - off, d3 = ev.w - off;
        f16x4 v;
        v[0] = (f16)(av.x * __expf(cf * d0 * d0));
        v[1] = (f16)(av.y * __expf(cf * d1 * d1));
        v[2] = (f16)(av.z * __expf(cf * d2 * d2));
        v[3] = (f16)(av.w * __expf(cf * d3 * d3));
        *(f16x4*)(Tsh + g * TS + j0) = v;
    }
    if (tid < 128) {                              // row 32 = A itself
        f16x4 v;
        v[0] = (f16)av.x; v[1] = (f16)av.y; v[2] = (f16)av.z; v[3] = (f16)av.w;
        *(f16x4*)(Tsh + 32 * TS + j0) = v;
    }
    __syncthreads();

    // ---- MFMA K-loop (K-split) ----
    const int kh = w >> 1;                        // k-half: 0 or 1
    const int nh = w & 1;                         // f-half: 0 or 1

    f32x4 acc[3][4];
    #pragma unroll
    for (int mt = 0; mt < 3; ++mt)
        #pragma unroll
        for (int nt = 0; nt < 4; ++nt)
            acc[mt][nt] = (f32x4){0.f, 0.f, 0.f, 0.f};

    const f16* Abase = Tsh + n * TS + kh * 256 + q * 8;
    const f16* A2base = Tsh + 32 * TS + kh * 256 + q * 8;   // broadcast row 32
    const f16* Bbase = rfT + (size_t)b * (NF * NN) + (nh * 64 + n) * NN + kh * 256 + q * 8;

    #pragma unroll
    for (int kk = 0; kk < 8; ++kk) {
        f16x8 bcur[4];
        #pragma unroll
        for (int nt = 0; nt < 4; ++nt)
            bcur[nt] = *(const f16x8*)(Bbase + kk * 32 + nt * 16 * NN);
        const f16x8 a0 = *(const f16x8*)(Abase + kk * 32);
        const f16x8 a1 = *(const f16x8*)(Abase + 16 * TS + kk * 32);
        const f16x8 a2 = *(const f16x8*)(A2base + kk * 32);
        #pragma unroll
        for (int nt = 0; nt < 4; ++nt) {
            acc[0][nt] = __builtin_amdgcn_mfma_f32_16x16x32_f16(a0, bcur[nt], acc[0][nt], 0, 0, 0);
            acc[1][nt] = __builtin_amdgcn_mfma_f32_16x16x32_f16(a1, bcur[nt], acc[1][nt], 0, 0, 0);
            acc[2][nt] = __builtin_amdgcn_mfma_f32_16x16x32_f16(a2, bcur[nt], acc[2][nt], 0, 0, 0);
        }
    }

    __syncthreads();                              // all T reads done; reuse as S
    // Each kh-half writes its own partial-S region (no RMW, no extra barrier)
    float* Sp = smem + kh * (33 * SS);
    #pragma unroll
    for (int mt = 0; mt < 2; ++mt)
        #pragma unroll
        for (int nt = 0; nt < 4; ++nt)
            #pragma unroll
            for (int rr = 0; rr < 4; ++rr)
                Sp[(mt * 16 + q * 4 + rr) * SS + nh * 64 + nt * 16 + n] = acc[mt][nt][rr];
    if (q == 0) {
        #pragma unroll
        for (int nt = 0; nt < 4; ++nt)
            Sp[32 * SS + nh * 64 + nt * 16 + n] = acc[2][nt][0];
    }
    __syncthreads();

    // ---- y[f] = sum_g W_df2[g,f]*(S0+S1)[g,f] + b_df2[f]*(S0+S1)[32,f] ----
    {
        const float* S0 = smem;
        const float* S1 = smem + 33 * SS;
        const int f = tid & 127;
        float a;
        if (tid < 128) {
            a = b_df2[f] * (S0[32 * SS + f] + S1[32 * SS + f]);
            #pragma unroll
            for (int g = 0; g < 16; ++g)
                a += W_df2[g * NF + f] * (S0[g * SS + f] + S1[g * SS + f]);
        } else {
            a = 0.f;
            #pragma unroll
            for (int g = 16; g < 32; ++g)
                a += W_df2[g * NF + f] * (S0[g * SS + f] + S1[g * SS + f]);
        }
        spart[tid >> 7][f] = a;
    }
    __syncthreads();
    if (tid < 128) sy[tid] = spart[0][tid] + spart[1][tid];
    __syncthreads();

    // ---- MLP layer 1: h = ssp(y @ W_d1 + b_d1) ----
    {
        const int f = tid & 127, hh = tid >> 7;
        float a = 0.f;
        #pragma unroll 8
        for (int k = hh * 64; k < hh * 64 + 64; ++k)
            a += sy[k] * W_d1[k * NAB + f];
        spart[hh][f] = a;
    }
    __syncthreads();
    float hreg = 0.f;
    if (tid < NAB) {
        const float x = spart[0][tid] + spart[1][tid] + b_d1[tid];
        const float sp = (x > 0.f) ? (x + log1pf(__expf(-x))) : log1pf(__expf(x));
        hreg = sp - 0.69314718055994530942f;
    }
    __syncthreads();
    if (tid < NAB) sy[tid] = hreg;
    __syncthreads();

    // ---- MLP layer 2: out = h @ W_d2 + b_d2 ----
    {
        const int f = tid & 127, hh = tid >> 7;
        float a = 0.f;
        #pragma unroll 8
        for (int k = hh * 64; k < hh * 64 + 64; ++k)
            a += sy[k] * W_d2[k * NAB + f];
        spart[hh][f] = a;
    }
    __syncthreads();
    if (tid < NAB)
        out[bi * NAB + tid] = spart[0][tid] + spart[1][tid] + b_d2[tid];
}

// ---------------------------------------------------------------------------
extern "C" void kernel_launch(void* const* d_in, const int* in_sizes, int n_in,
                              void* d_out, int out_size, void* d_ws, size_t ws_size,
                              hipStream_t stream) {
    const float* r       = (const float*)d_in[0];
    const float* e       = (const float*)d_in[1];
    const float* A       = (const float*)d_in[2];
    const float* offsets = (const float*)d_in[3];
    const float* widths  = (const float*)d_in[4];
    // d_in[5]/d_in[6]: W_df1/b_df1 — reference discards this branch
    const float* W_df2   = (const float*)d_in[7];
    const float* b_df2   = (const float*)d_in[8];
    const float* W_af    = (const float*)d_in[9];
    const float* W_d1    = (const float*)d_in[10];
    const float* b_d1    = (const float*)d_in[11];
    const float* W_d2    = (const float*)d_in[12];
    const float* b_d2    = (const float*)d_in[13];
    float* out = (float*)d_out;

    f16* rfT = (f16*)d_ws;                       // [B][128 f][512 j] f16 = 256 KB

    prep_rf<<<BB * NN / 4, 256, 0, stream>>>(r, W_af, rfT);
    fused_kernel<<<BB * NN, 256, 0, stream>>>(e, A, rfT, offsets, widths,
                                              W_df2, b_df2, W_d1, b_d1,
                                              W_d2, b_d2, out);
}